// Round 1
// baseline (1099.758 us; speedup 1.0000x reference)
//
#include <hip/hip_runtime.h>
#include <stdint.h>

#define T_TOK 8192
#define HD    1024
#define ID    2816
#define NE    8
#define RCAP  18432   // 16384 pairs + up to 8*256 padding (256-aligned expert segments)

typedef __bf16 bf16x8 __attribute__((ext_vector_type(8)));
typedef float  f32x4  __attribute__((ext_vector_type(4)));

__device__ __forceinline__ unsigned short f2bf(float f) {
  union { float f; unsigned u; } v; v.f = f;
  unsigned r = v.u + 0x7FFFu + ((v.u >> 16) & 1u);  // round-to-nearest-even
  return (unsigned short)(r >> 16);
}

__device__ __forceinline__ void gl16(const void* g, void* l) {
  __builtin_amdgcn_global_load_lds((__attribute__((address_space(1))) void*)g,
                                   (__attribute__((address_space(3))) void*)l,
                                   16, 0, 0);
}

// -------- scheduling primitives (counted-vmcnt phase pipeline) --------
#define VMCNT(n) asm volatile("s_waitcnt vmcnt(" #n ")" ::: "memory")
#define LGKM0    asm volatile("s_waitcnt lgkmcnt(0)" ::: "memory")
#define BARRIER  do { __builtin_amdgcn_s_barrier(); asm volatile("" ::: "memory"); } while (0)
#define PRIO1    __builtin_amdgcn_s_setprio(1)
#define PRIO0    __builtin_amdgcn_s_setprio(0)

// ---------------- K0a: x fp32 -> bf16 ----------------
__global__ void k_cvt_x(const float* __restrict__ x, unsigned short* __restrict__ xb) {
  const int i = blockIdx.x * blockDim.x + threadIdx.x;
  const float4 v = ((const float4*)x)[i];
  ushort4 o;
  o.x = f2bf(v.x); o.y = f2bf(v.y); o.z = f2bf(v.z); o.w = f2bf(v.w);
  ((ushort4*)xb)[i] = o;
}

// ---------------- K0b: transpose + convert weights ----------------
__global__ void k_transpose(const float* __restrict__ Wg, const float* __restrict__ Wu,
                            const float* __restrict__ Wd,
                            unsigned short* __restrict__ Wgt, unsigned short* __restrict__ Wut,
                            unsigned short* __restrict__ Wdt) {
  const int m = blockIdx.y;
  const float* src; unsigned short* dst; int R, C;
  if (m < 8)       { src = Wg + (size_t)m * HD * ID;        dst = Wgt + (size_t)m * HD * ID;        R = HD; C = ID; }
  else if (m < 16) { src = Wu + (size_t)(m - 8) * HD * ID;  dst = Wut + (size_t)(m - 8) * HD * ID;  R = HD; C = ID; }
  else             { src = Wd + (size_t)(m - 16) * HD * ID; dst = Wdt + (size_t)(m - 16) * HD * ID; R = ID; C = HD; }
  const int tc = C / 64;
  const int tr = blockIdx.x / tc, tcc = blockIdx.x % tc;
  const int r0 = tr * 64, c0 = tcc * 64;
  __shared__ __align__(16) unsigned short tl[64 * 64];
  const int t = threadIdx.x;
  const int rb = t >> 4;
  const int c4 = t & 15;
  const float* sp = src + (size_t)(r0 + rb * 4) * C + c0 + c4 * 4;
  float4 v[4];
#pragma unroll
  for (int i = 0; i < 4; ++i) v[i] = *(const float4*)(sp + (size_t)i * C);
  const float* vf = (const float*)v;
#pragma unroll
  for (int q = 0; q < 4; ++q) {
    const int c = c4 * 4 + q;
    ushort4 o;
    o.x = f2bf(vf[0 * 4 + q]); o.y = f2bf(vf[1 * 4 + q]);
    o.z = f2bf(vf[2 * 4 + q]); o.w = f2bf(vf[3 * 4 + q]);
    *(ushort4*)&tl[c * 64 + ((rb ^ (c & 15)) * 4)] = o;
  }
  __syncthreads();
  const int orow = t >> 2, seg = t & 3;
  __align__(16) unsigned short tmp[16];
#pragma unroll
  for (int mI = 0; mI < 4; ++mI) {
    const int s = seg * 4 + mI;
    *(ushort4*)&tmp[mI * 4] = *(const ushort4*)&tl[orow * 64 + ((s ^ (orow & 15)) * 4)];
  }
  unsigned short* dp = dst + (size_t)(c0 + orow) * R + r0 + seg * 16;
  ((uint4*)dp)[0] = ((const uint4*)tmp)[0];
  ((uint4*)dp)[1] = ((const uint4*)tmp)[1];
}

// ---------------- K1: router (1 token per wave) ----------------
__global__ void k_router(const float* __restrict__ x, const float* __restrict__ Wr,
                         int* __restrict__ cnt, float* __restrict__ psum,
                         int* __restrict__ tok_e, float* __restrict__ tok_w) {
  __shared__ float bp[NE];
  __shared__ int bc[NE];
  const int tid = threadIdx.x;
  if (tid < NE) { bp[tid] = 0.f; bc[tid] = 0; }
  __syncthreads();
  const int lane = tid & 63, w = tid >> 6;
  const int t = blockIdx.x * 4 + w;
  float acc[NE] = {0.f, 0.f, 0.f, 0.f, 0.f, 0.f, 0.f, 0.f};
  for (int h = lane; h < HD; h += 64) {
    const float xv = x[(size_t)t * HD + h];
    const float4 w0 = *(const float4*)(Wr + h * 8);
    const float4 w1 = *(const float4*)(Wr + h * 8 + 4);
    acc[0] += xv * w0.x; acc[1] += xv * w0.y; acc[2] += xv * w0.z; acc[3] += xv * w0.w;
    acc[4] += xv * w1.x; acc[5] += xv * w1.y; acc[6] += xv * w1.z; acc[7] += xv * w1.w;
  }
#pragma unroll
  for (int e = 0; e < NE; ++e)
    for (int off = 32; off > 0; off >>= 1)
      acc[e] += __shfl_xor(acc[e], off, 64);
  if (lane == 0) {
    float mx = acc[0];
    for (int e = 1; e < NE; ++e) mx = fmaxf(mx, acc[e]);
    float p[NE], s = 0.f;
    for (int e = 0; e < NE; ++e) { p[e] = __expf(acc[e] - mx); s += p[e]; }
    const float inv = 1.f / s;
    for (int e = 0; e < NE; ++e) p[e] *= inv;
    int e0 = 0;
    for (int e = 1; e < NE; ++e) if (p[e] > p[e0]) e0 = e;
    int e1 = (e0 == 0) ? 1 : 0;
    for (int e = 0; e < NE; ++e) if (e != e0 && p[e] > p[e1]) e1 = e;
    const float v0 = p[e0], v1 = p[e1];
    const float invs = 1.f / (v0 + v1 + 1e-9f);
    tok_e[2 * t] = e0;          tok_e[2 * t + 1] = e1;
    tok_w[2 * t] = v0 * invs;   tok_w[2 * t + 1] = v1 * invs;
    atomicAdd(&bc[e0], 1); atomicAdd(&bc[e1], 1);
    for (int e = 0; e < NE; ++e) atomicAdd(&bp[e], p[e]);
  }
  __syncthreads();
  if (tid < NE) { atomicAdd(&cnt[tid], bc[tid]); atomicAdd(&psum[tid], bp[tid]); }
}

// ---------------- K2: offsets + aux loss + pad sentinels (256-aligned) ----------------
__global__ void k_offsets(const int* __restrict__ cnt, const float* __restrict__ psum,
                          int* __restrict__ offp, int* __restrict__ pair_tok,
                          float* __restrict__ pair_w, float* __restrict__ loss_out) {
  __shared__ int soff[NE + 1], scnt[NE];
  if (threadIdx.x == 0) {
    int o = 0;
    for (int e = 0; e < NE; ++e) {
      soff[e] = o; scnt[e] = cnt[e];
      o += (scnt[e] + 255) & ~255;
    }
    soff[NE] = o;
    for (int e = 0; e <= NE; ++e) offp[e] = soff[e];
    float loss = 0.f;
    for (int e = 0; e < NE; ++e) loss += psum[e] * (float)scnt[e];
    loss *= (float)NE * 0.01f / ((float)T_TOK * (float)T_TOK);
    *loss_out = loss;
  }
  __syncthreads();
  for (int e = 0; e < NE; ++e) {
    const int base = soff[e] + scnt[e];
    const int n = soff[e + 1] - base;
    for (int j = threadIdx.x; j < n; j += blockDim.x) {
      pair_tok[base + j] = -1;
      pair_w[base + j] = 0.f;
    }
  }
}

// ---------------- K3: compaction (+ inverse map) ----------------
__global__ void k_scatter(const int* __restrict__ tok_e, const float* __restrict__ tok_w,
                          const int* __restrict__ offp, int* __restrict__ cursor,
                          int* __restrict__ pair_tok, float* __restrict__ pair_w,
                          int* __restrict__ inv_p) {
  const int t = blockIdx.x * 256 + threadIdx.x;
#pragma unroll
  for (int k = 0; k < 2; ++k) {
    const int e = tok_e[2 * t + k];
    const int pos = atomicAdd(&cursor[e], 1);
    const int idx = offp[e] + pos;
    pair_tok[idx] = t;
    pair_w[idx] = tok_w[2 * t + k];
    inv_p[2 * t + k] = idx;
  }
}

// ---------------- K4: stage1 — phase-scheduled 256x128 dual-B GEMM + SwiGLU ----------------
// BM=256 rows, BN=128 i-cols (gate+up), BK=64, NT=16 K-tiles.
// 8 waves as 4M x 2N (64x64 per wave, both matrices). 4 phases/tile:
//   P1 gate-kk0, P2 up-kk0 (A frags reused), P3 gate-kk1, P4 up-kk1.
// Staging into freed sub-regions (depth-2 prefetch with 2 LDS buffers):
//   P1: Bu-kk1 of tile T+1 (other buffer); P2: A-kk0 + Bg-kk0 of T+2;
//   P3: Bu-kk0 of T+2; P4: A-kk1 + Bg-kk1 of T+2.
// One counted vmcnt(7) per tile boundary (T+1's last round has 7 newer rounds).
// LDS ushort map: A [buf][kkh][256][32] @0; Bg [buf][kkh][128][32] @32768; Bu @49152.
#define A_RG(b,h)  ((b) * 16384 + (h) * 8192)
#define BG_RG(b,h) (32768 + (b) * 8192 + (h) * 4096)
#define BU_RG(b,h) (49152 + (b) * 8192 + (h) * 4096)
#define STG_A(b,h,t)  do { gl16(srcA0 + (t) * 64 + (h) * 32, &smem[A_RG(b,h) + wub]); \
                           gl16(srcA1 + (t) * 64 + (h) * 32, &smem[A_RG(b,h) + 4096 + wub]); } while (0)
#define STG_BG(b,h,t) gl16(srcBg + (t) * 64 + (h) * 32, &smem[BG_RG(b,h) + wub])
#define STG_BU(b,h,t) gl16(srcBu + (t) * 64 + (h) * 32, &smem[BU_RG(b,h) + wub])

#define S1_RD_AF(b,k) { _Pragma("unroll") for (int mf_ = 0; mf_ < 4; ++mf_) \
                          af[mf_] = *(const bf16x8*)&smem[A_RG(b,k) + afoff[mf_]]; }
#define S1_RD_BG(b,k) { _Pragma("unroll") for (int nf_ = 0; nf_ < 4; ++nf_) \
                          bg[nf_] = *(const bf16x8*)&smem[BG_RG(b,k) + bnoff[nf_]]; }
#define S1_RD_BU(b,k) { _Pragma("unroll") for (int nf_ = 0; nf_ < 4; ++nf_) \
                          bu[nf_] = *(const bf16x8*)&smem[BU_RG(b,k) + bnoff[nf_]]; }
#define S1_MM(ACC, BF) { _Pragma("unroll") for (int mf_ = 0; mf_ < 4; ++mf_) { \
                           _Pragma("unroll") for (int nf_ = 0; nf_ < 4; ++nf_) \
                             ACC[mf_][nf_] = __builtin_amdgcn_mfma_f32_16x16x32_bf16(af[mf_], BF[nf_], ACC[mf_][nf_], 0, 0, 0); } }

#define S1_TILE(B, KT) do { \
    bf16x8 af[4], bg[4], bu[4]; \
    /* P1: gate kk0 */ \
    S1_RD_AF(B, 0); S1_RD_BG(B, 0); \
    if ((KT) + 1 < 16) STG_BU((B) ^ 1, 1, (KT) + 1); \
    BARRIER; LGKM0; PRIO1; S1_MM(accg, bg); PRIO0; BARRIER; \
    /* P2: up kk0 (af reused) */ \
    S1_RD_BU(B, 0); \
    if ((KT) + 2 < 16) { STG_A(B, 0, (KT) + 2); STG_BG(B, 0, (KT) + 2); } \
    BARRIER; LGKM0; PRIO1; S1_MM(accu, bu); PRIO0; BARRIER; \
    /* P3: gate kk1 */ \
    S1_RD_AF(B, 1); S1_RD_BG(B, 1); \
    if ((KT) + 2 < 16) STG_BU(B, 0, (KT) + 2); \
    BARRIER; LGKM0; PRIO1; S1_MM(accg, bg); PRIO0; BARRIER; \
    /* P4: up kk1 */ \
    S1_RD_BU(B, 1); \
    if ((KT) + 2 < 16) { STG_A(B, 1, (KT) + 2); STG_BG(B, 1, (KT) + 2); } \
    BARRIER; LGKM0; PRIO1; S1_MM(accu, bu); PRIO0; \
    if ((KT) + 2 < 16) { VMCNT(7); } else { VMCNT(0); } \
    BARRIER; \
  } while (0)

__launch_bounds__(512, 2)
__global__ void k_stage1(const unsigned short* __restrict__ xb,
                         const unsigned short* __restrict__ Wgt,
                         const unsigned short* __restrict__ Wut,
                         const int* __restrict__ offp,
                         const int* __restrict__ pair_tok,
                         unsigned short* __restrict__ act) {
  __shared__ __align__(16) unsigned short smem[65536];   // 128 KiB
  __shared__ int toks[256];

  // bijective XCD swizzle over 1584 = 22 x 72 blocks (1584 % 8 == 0)
  int wg = blockIdx.x;
  wg = (wg & 7) * (1584 / 8) + (wg >> 3);
  const int ytile = wg / 22, xtile = wg - ytile * 22;
  const int row0 = ytile * 256;
  if (row0 >= offp[8]) return;
  int e = 0;
  while (offp[e + 1] <= row0) ++e;
  const int i0 = xtile * 128;

  const int tid = threadIdx.x;
  if (tid < 256) {
    const int tk = pair_tok[row0 + tid];
    toks[tid] = tk < 0 ? 0 : tk;
  }
  __syncthreads();

  const int l = tid & 63, w = tid >> 6;
  const int colm = l & 15, quad = l >> 4;
  const int wr = w >> 1, wc = w & 1;

  // staging mapping: wave w covers rows w*16 + l/4; slot l&3; source pre-swizzled
  const int rA0 = w * 16 + (l >> 2);
  const int ks  = (l & 3) ^ ((l >> 2) & 3);
  const unsigned short* wgtE = Wgt + (size_t)e * ID * HD;
  const unsigned short* wutE = Wut + (size_t)e * ID * HD;
  const unsigned short* srcA0 = xb + (size_t)toks[rA0] * HD + ks * 8;
  const unsigned short* srcA1 = xb + (size_t)toks[rA0 + 128] * HD + ks * 8;
  const unsigned short* srcBg = wgtE + (size_t)(i0 + rA0) * HD + ks * 8;
  const unsigned short* srcBu = wutE + (size_t)(i0 + rA0) * HD + ks * 8;
  const int wub = w * 512;

  // fragment read offsets (slot = quad ^ (row&3), row&3 == colm&3)
  const int sl = (quad ^ (colm & 3)) * 8;
  int afoff[4], bnoff[4];
#pragma unroll
  for (int i = 0; i < 4; ++i) {
    afoff[i] = (wr * 64 + i * 16 + colm) * 32 + sl;
    bnoff[i] = (wc * 64 + i * 16 + colm) * 32 + sl;
  }

  const f32x4 zero = {0.f, 0.f, 0.f, 0.f};
  f32x4 accg[4][4], accu[4][4];
#pragma unroll
  for (int a = 0; a < 4; ++a)
#pragma unroll
    for (int b = 0; b < 4; ++b) { accg[a][b] = zero; accu[a][b] = zero; }

  // prologue: tile0 full (8 rounds), tile1 minus Bu-kk1 (7 rounds)
  STG_A(0, 0, 0); STG_BG(0, 0, 0); STG_BU(0, 0, 0);
  STG_A(0, 1, 0); STG_BG(0, 1, 0); STG_BU(0, 1, 0);
  STG_A(1, 0, 1); STG_BG(1, 0, 1); STG_BU(1, 0, 1);
  STG_A(1, 1, 1); STG_BG(1, 1, 1);
  VMCNT(7); BARRIER;

  for (int kt = 0; kt < 16; kt += 2) {
    S1_TILE(0, kt);
    S1_TILE(1, kt + 1);
  }

  // epilogue: SwiGLU, write bf16 activations
#pragma unroll
  for (int mf = 0; mf < 4; ++mf) {
#pragma unroll
    for (int r = 0; r < 4; ++r) {
      const int orow = row0 + wr * 64 + mf * 16 + quad * 4 + r;
      unsigned short* arow = act + (size_t)orow * ID + i0 + wc * 64 + colm;
#pragma unroll
      for (int nf = 0; nf < 4; ++nf) {
        const float g = accg[mf][nf][r];
        const float u = accu[mf][nf][r];
        const float h = (g / (1.f + __expf(-g))) * u;
        arow[nf * 16] = f2bf(h);
      }
    }
  }
}

// ---------------- K5: stage2 — phase-scheduled 256x128 down GEMM ----------------
// BM=256, BN=128, BK=64, NT=44. 8 waves 4M x 2N. 2 phases/tile (kk0, kk1).
// Staging: P1 stages kk1 of T+1 (other buffer, freed at T-1's P2);
//          P2 stages kk0 of T+2 (this buffer, freed at P1).
// vmcnt(6) per phase (data read 3 phases after issue; 2 newer phases x 3 rounds).
// LDS ushort map: A [buf][kkh][256][32] @0; B [buf][kkh][128][32] @32768. 96 KiB.
#define A2_RG(b,h) ((b) * 16384 + (h) * 8192)
#define B2_RG(b,h) (32768 + (b) * 8192 + (h) * 4096)
#define STG2_A(b,h,t) do { gl16(srcA0 + (t) * 64 + (h) * 32, &smem[A2_RG(b,h) + wub]); \
                           gl16(srcA1 + (t) * 64 + (h) * 32, &smem[A2_RG(b,h) + 4096 + wub]); } while (0)
#define STG2_B(b,h,t) gl16(srcB + (t) * 64 + (h) * 32, &smem[B2_RG(b,h) + wub])

#define S2_RD_AF(b,k) { _Pragma("unroll") for (int mf_ = 0; mf_ < 4; ++mf_) \
                          af[mf_] = *(const bf16x8*)&smem[A2_RG(b,k) + afoff[mf_]]; }
#define S2_RD_BF(b,k) { _Pragma("unroll") for (int nf_ = 0; nf_ < 4; ++nf_) \
                          bf_[nf_] = *(const bf16x8*)&smem[B2_RG(b,k) + bnoff[nf_]]; }
#define S2_MM { _Pragma("unroll") for (int mf_ = 0; mf_ < 4; ++mf_) { \
                  _Pragma("unroll") for (int nf_ = 0; nf_ < 4; ++nf_) \
                    acc[mf_][nf_] = __builtin_amdgcn_mfma_f32_16x16x32_bf16(af[mf_], bf_[nf_], acc[mf_][nf_], 0, 0, 0); } }

#define S2_TILE(B, T) do { \
    bf16x8 af[4], bf_[4]; \
    /* P1: kk0 */ \
    S2_RD_AF(B, 0); S2_RD_BF(B, 0); \
    if ((T) + 1 < 44) { STG2_A((B) ^ 1, 1, (T) + 1); STG2_B((B) ^ 1, 1, (T) + 1); } \
    BARRIER; LGKM0; PRIO1; S2_MM; PRIO0; \
    if ((T) + 1 < 44) { VMCNT(6); } else { VMCNT(0); } \
    BARRIER; \
    /* P2: kk1 */ \
    S2_RD_AF(B, 1); S2_RD_BF(B, 1); \
    if ((T) + 2 < 44) { STG2_A(B, 0, (T) + 2); STG2_B(B, 0, (T) + 2); } \
    BARRIER; LGKM0; PRIO1; S2_MM; PRIO0; \
    if ((T) + 2 < 44) { VMCNT(6); } else if ((T) + 1 < 44) { VMCNT(3); } else { VMCNT(0); } \
    BARRIER; \
  } while (0)

template <bool USE_CONTRIB>
__launch_bounds__(512, 2)
__global__ void k_stage2_t(const unsigned short* __restrict__ act,
                           const unsigned short* __restrict__ Wdt,
                           const int* __restrict__ offp,
                           const int* __restrict__ pair_tok,
                           const float* __restrict__ pair_w,
                           float* __restrict__ contrib,   // USE_CONTRIB: [RCAP][HD]
                           float* __restrict__ out) {     // !USE_CONTRIB: atomic path
  __shared__ __align__(16) unsigned short smem[49152];    // 96 KiB
  __shared__ int toks[256];
  __shared__ float wts[256];

  // bijective XCD swizzle over 576 = 8 x 72 blocks
  int wg = blockIdx.x;
  wg = (wg & 7) * (576 / 8) + (wg >> 3);
  const int ytile = wg >> 3, xtile = wg & 7;
  const int row0 = ytile * 256;
  if (row0 >= offp[8]) return;
  int e = 0;
  while (offp[e + 1] <= row0) ++e;
  const int h0 = xtile * 128;
  const int tid = threadIdx.x;
  if (!USE_CONTRIB && tid < 256) {
    toks[tid] = pair_tok[row0 + tid];
    wts[tid] = pair_w[row0 + tid];
  }

  const int l = tid & 63, w = tid >> 6;
  const int colm = l & 15, quad = l >> 4;
  const int wr = w >> 1, wc = w & 1;
  const int rA0 = w * 16 + (l >> 2);
  const int ks = (l & 3) ^ ((l >> 2) & 3);
  const unsigned short* wdE = Wdt + (size_t)e * HD * ID;
  const unsigned short* srcA0 = act + (size_t)(row0 + rA0) * ID + ks * 8;
  const unsigned short* srcA1 = act + (size_t)(row0 + rA0 + 128) * ID + ks * 8;
  const unsigned short* srcB  = wdE + (size_t)(h0 + rA0) * ID + ks * 8;
  const int wub = w * 512;
  const int sl = (quad ^ (colm & 3)) * 8;
  int afoff[4], bnoff[4];
#pragma unroll
  for (int i = 0; i < 4; ++i) {
    afoff[i] = (wr * 64 + i * 16 + colm) * 32 + sl;
    bnoff[i] = (wc * 64 + i * 16 + colm) * 32 + sl;
  }

  const f32x4 zero = {0.f, 0.f, 0.f, 0.f};
  f32x4 acc[4][4];
#pragma unroll
  for (int a = 0; a < 4; ++a)
#pragma unroll
    for (int b = 0; b < 4; ++b) acc[a][b] = zero;

  // prologue: tile0 full (6 rounds), tile1 kk0 (3 rounds); kk1 of tile1 staged at T0-P1
  STG2_A(0, 0, 0); STG2_B(0, 0, 0);
  STG2_A(0, 1, 0); STG2_B(0, 1, 0);
  STG2_A(1, 0, 1); STG2_B(1, 0, 1);
  VMCNT(3); BARRIER;

  for (int T = 0; T < 44; T += 2) {
    S2_TILE(0, T);
    S2_TILE(1, T + 1);
  }

#pragma unroll
  for (int mf = 0; mf < 4; ++mf) {
#pragma unroll
    for (int r = 0; r < 4; ++r) {
      const int lrow = wr * 64 + mf * 16 + quad * 4 + r;
      if (USE_CONTRIB) {
        float* crow = contrib + (size_t)(row0 + lrow) * HD + h0 + wc * 64 + colm;
#pragma unroll
        for (int nf = 0; nf < 4; ++nf)
          crow[nf * 16] = acc[mf][nf][r];
      } else {
        const int t = toks[lrow];
        if (t < 0) continue;
        const float wt = wts[lrow];
        float* orow = out + (size_t)t * HD + h0 + wc * 64 + colm;
#pragma unroll
        for (int nf = 0; nf < 4; ++nf)
          atomicAdd(&orow[nf * 16], wt * acc[mf][nf][r]);
      }
    }
  }
}

// ---------------- K6: combine (contrib path) ----------------
__global__ void k_combine(const float* __restrict__ contrib, const int* __restrict__ inv_p,
                          const float* __restrict__ tok_w, float* __restrict__ out) {
  const int t = blockIdx.x;
  const int h4 = threadIdx.x;
  const int p0 = inv_p[2 * t], p1 = inv_p[2 * t + 1];
  const float w0 = tok_w[2 * t], w1 = tok_w[2 * t + 1];
  const float4 a = ((const float4*)(contrib + (size_t)p0 * HD))[h4];
  const float4 b = ((const float4*)(contrib + (size_t)p1 * HD))[h4];
  float4 o;
  o.x = w0 * a.x + w1 * b.x;
  o.y = w0 * a.y + w1 * b.y;
  o.z = w0 * a.z + w1 * b.z;
  o.w = w0 * a.w + w1 * b.w;
  ((float4*)(out + (size_t)t * HD))[h4] = o;
}

extern "C" void kernel_launch(void* const* d_in, const int* in_sizes, int n_in,
                              void* d_out, int out_size, void* d_ws, size_t ws_size,
                              hipStream_t stream) {
  const float* x  = (const float*)d_in[0];
  const float* Wr = (const float*)d_in[1];
  const float* Wg = (const float*)d_in[2];
  const float* Wu = (const float*)d_in[3];
  const float* Wd = (const float*)d_in[4];
  float* out = (float*)d_out;

  char* ws = (char*)d_ws;
  const size_t off_xb  = 256;
  const size_t sz_xb   = (size_t)T_TOK * HD * 2;
  const size_t sz_w    = (size_t)NE * HD * ID * 2;
  const size_t off_wgt = off_xb + sz_xb;
  const size_t off_wut = off_wgt + sz_w;
  const size_t off_wdt = off_wut + sz_w;
  const size_t off_act = off_wdt + sz_w;
  const size_t sz_act  = (size_t)RCAP * ID * 2;
  const size_t off_ptk = off_act + sz_act;
  const size_t off_pw  = off_ptk + (size_t)RCAP * 4;
  const size_t off_te  = off_pw + (size_t)RCAP * 4;
  const size_t off_tw  = off_te + (size_t)T_TOK * 2 * 4;
  const size_t off_ip  = off_tw + (size_t)T_TOK * 2 * 4;
  const size_t off_ctb = off_ip + (size_t)T_TOK * 2 * 4;
  const size_t need_base = off_ctb;
  const size_t need_full = off_ctb + (size_t)RCAP * HD * 4;
  if (ws_size < need_base) return;
  const bool use_contrib = (ws_size >= need_full);

  int*   cnt    = (int*)(ws + 0);
  float* psum   = (float*)(ws + 32);
  int*   cursor = (int*)(ws + 64);
  int*   offp   = (int*)(ws + 96);
  unsigned short* xb  = (unsigned short*)(ws + off_xb);
  unsigned short* Wgt = (unsigned short*)(ws + off_wgt);
  unsigned short* Wut = (unsigned short*)(ws + off_wut);
  unsigned short* Wdt = (unsigned short*)(ws + off_wdt);
  unsigned short* act = (unsigned short*)(ws + off_act);
  int*   pair_tok = (int*)(ws + off_ptk);
  float* pair_w   = (float*)(ws + off_pw);
  int*   tok_e    = (int*)(ws + off_te);
  float* tok_w    = (float*)(ws + off_tw);
  int*   inv_p    = (int*)(ws + off_ip);
  float* contrib  = (float*)(ws + off_ctb);

  hipMemsetAsync(ws, 0, 256, stream);
  if (!use_contrib)
    hipMemsetAsync(out, 0, (size_t)T_TOK * HD * sizeof(float), stream);

  k_cvt_x<<<(T_TOK * HD / 4) / 256, 256, 0, stream>>>(x, xb);
  k_transpose<<<dim3(704, 24), 256, 0, stream>>>(Wg, Wu, Wd, Wgt, Wut, Wdt);
  k_router<<<T_TOK / 4, 256, 0, stream>>>(x, Wr, cnt, psum, tok_e, tok_w);
  k_offsets<<<1, 256, 0, stream>>>(cnt, psum, offp, pair_tok, pair_w, out + (size_t)T_TOK * HD);
  k_scatter<<<T_TOK / 256, 256, 0, stream>>>(tok_e, tok_w, offp, cursor, pair_tok, pair_w, inv_p);
  k_stage1<<<(ID / 128) * (RCAP / 256), 512, 0, stream>>>(xb, Wgt, Wut, offp, pair_tok, act);
  if (use_contrib) {
    k_stage2_t<true><<<(HD / 128) * (RCAP / 256), 512, 0, stream>>>(act, Wdt, offp, pair_tok, pair_w, contrib, out);
    k_combine<<<T_TOK, 256, 0, stream>>>(contrib, inv_p, tok_w, out);
  } else {
    k_stage2_t<false><<<(HD / 128) * (RCAP / 256), 512, 0, stream>>>(act, Wdt, offp, pair_tok, pair_w, contrib, out);
  }
}

// Round 2
// 1074.750 us; speedup vs baseline: 1.0233x; 1.0233x over previous
//
#include <hip/hip_runtime.h>
#include <stdint.h>

#define T_TOK 8192
#define HD    1024
#define ID    2816
#define NE    8
#define RCAP  18432   // 16384 pairs + up to 8*256 padding (256-aligned expert segments)

typedef __bf16 bf16x8 __attribute__((ext_vector_type(8)));
typedef float  f32x4  __attribute__((ext_vector_type(4)));

__device__ __forceinline__ unsigned short f2bf(float f) {
  union { float f; unsigned u; } v; v.f = f;
  unsigned r = v.u + 0x7FFFu + ((v.u >> 16) & 1u);  // round-to-nearest-even
  return (unsigned short)(r >> 16);
}

__device__ __forceinline__ void gl16(const void* g, void* l) {
  __builtin_amdgcn_global_load_lds((__attribute__((address_space(1))) void*)g,
                                   (__attribute__((address_space(3))) void*)l,
                                   16, 0, 0);
}

// -------- scheduling primitives (counted-vmcnt phase pipeline) --------
#define VMCNT(n) asm volatile("s_waitcnt vmcnt(" #n ")" ::: "memory")
#define LGKM0    asm volatile("s_waitcnt lgkmcnt(0)" ::: "memory")
#define BARRIER  do { __builtin_amdgcn_s_barrier(); asm volatile("" ::: "memory"); } while (0)
#define PRIO1    __builtin_amdgcn_s_setprio(1)
#define PRIO0    __builtin_amdgcn_s_setprio(0)

// ---------------- K0a: x fp32 -> bf16 ----------------
__global__ void k_cvt_x(const float* __restrict__ x, unsigned short* __restrict__ xb) {
  const int i = blockIdx.x * blockDim.x + threadIdx.x;
  const float4 v = ((const float4*)x)[i];
  ushort4 o;
  o.x = f2bf(v.x); o.y = f2bf(v.y); o.z = f2bf(v.z); o.w = f2bf(v.w);
  ((ushort4*)xb)[i] = o;
}

// ---------------- K0b: transpose + convert weights ----------------
__global__ void k_transpose(const float* __restrict__ Wg, const float* __restrict__ Wu,
                            const float* __restrict__ Wd,
                            unsigned short* __restrict__ Wgt, unsigned short* __restrict__ Wut,
                            unsigned short* __restrict__ Wdt) {
  const int m = blockIdx.y;
  const float* src; unsigned short* dst; int R, C;
  if (m < 8)       { src = Wg + (size_t)m * HD * ID;        dst = Wgt + (size_t)m * HD * ID;        R = HD; C = ID; }
  else if (m < 16) { src = Wu + (size_t)(m - 8) * HD * ID;  dst = Wut + (size_t)(m - 8) * HD * ID;  R = HD; C = ID; }
  else             { src = Wd + (size_t)(m - 16) * HD * ID; dst = Wdt + (size_t)(m - 16) * HD * ID; R = ID; C = HD; }
  const int tc = C / 64;
  const int tr = blockIdx.x / tc, tcc = blockIdx.x % tc;
  const int r0 = tr * 64, c0 = tcc * 64;
  __shared__ __align__(16) unsigned short tl[64 * 64];
  const int t = threadIdx.x;
  const int rb = t >> 4;
  const int c4 = t & 15;
  const float* sp = src + (size_t)(r0 + rb * 4) * C + c0 + c4 * 4;
  float4 v[4];
#pragma unroll
  for (int i = 0; i < 4; ++i) v[i] = *(const float4*)(sp + (size_t)i * C);
  const float* vf = (const float*)v;
#pragma unroll
  for (int q = 0; q < 4; ++q) {
    const int c = c4 * 4 + q;
    ushort4 o;
    o.x = f2bf(vf[0 * 4 + q]); o.y = f2bf(vf[1 * 4 + q]);
    o.z = f2bf(vf[2 * 4 + q]); o.w = f2bf(vf[3 * 4 + q]);
    *(ushort4*)&tl[c * 64 + ((rb ^ (c & 15)) * 4)] = o;
  }
  __syncthreads();
  const int orow = t >> 2, seg = t & 3;
  __align__(16) unsigned short tmp[16];
#pragma unroll
  for (int mI = 0; mI < 4; ++mI) {
    const int s = seg * 4 + mI;
    *(ushort4*)&tmp[mI * 4] = *(const ushort4*)&tl[orow * 64 + ((s ^ (orow & 15)) * 4)];
  }
  unsigned short* dp = dst + (size_t)(c0 + orow) * R + r0 + seg * 16;
  ((uint4*)dp)[0] = ((const uint4*)tmp)[0];
  ((uint4*)dp)[1] = ((const uint4*)tmp)[1];
}

// ---------------- K1: router (1 token per wave) ----------------
__global__ void k_router(const float* __restrict__ x, const float* __restrict__ Wr,
                         int* __restrict__ cnt, float* __restrict__ psum,
                         int* __restrict__ tok_e, float* __restrict__ tok_w) {
  __shared__ float bp[NE];
  __shared__ int bc[NE];
  const int tid = threadIdx.x;
  if (tid < NE) { bp[tid] = 0.f; bc[tid] = 0; }
  __syncthreads();
  const int lane = tid & 63, w = tid >> 6;
  const int t = blockIdx.x * 4 + w;
  float acc[NE] = {0.f, 0.f, 0.f, 0.f, 0.f, 0.f, 0.f, 0.f};
  for (int h = lane; h < HD; h += 64) {
    const float xv = x[(size_t)t * HD + h];
    const float4 w0 = *(const float4*)(Wr + h * 8);
    const float4 w1 = *(const float4*)(Wr + h * 8 + 4);
    acc[0] += xv * w0.x; acc[1] += xv * w0.y; acc[2] += xv * w0.z; acc[3] += xv * w0.w;
    acc[4] += xv * w1.x; acc[5] += xv * w1.y; acc[6] += xv * w1.z; acc[7] += xv * w1.w;
  }
#pragma unroll
  for (int e = 0; e < NE; ++e)
    for (int off = 32; off > 0; off >>= 1)
      acc[e] += __shfl_xor(acc[e], off, 64);
  if (lane == 0) {
    float mx = acc[0];
    for (int e = 1; e < NE; ++e) mx = fmaxf(mx, acc[e]);
    float p[NE], s = 0.f;
    for (int e = 0; e < NE; ++e) { p[e] = __expf(acc[e] - mx); s += p[e]; }
    const float inv = 1.f / s;
    for (int e = 0; e < NE; ++e) p[e] *= inv;
    int e0 = 0;
    for (int e = 1; e < NE; ++e) if (p[e] > p[e0]) e0 = e;
    int e1 = (e0 == 0) ? 1 : 0;
    for (int e = 0; e < NE; ++e) if (e != e0 && p[e] > p[e1]) e1 = e;
    const float v0 = p[e0], v1 = p[e1];
    const float invs = 1.f / (v0 + v1 + 1e-9f);
    tok_e[2 * t] = e0;          tok_e[2 * t + 1] = e1;
    tok_w[2 * t] = v0 * invs;   tok_w[2 * t + 1] = v1 * invs;
    atomicAdd(&bc[e0], 1); atomicAdd(&bc[e1], 1);
    for (int e = 0; e < NE; ++e) atomicAdd(&bp[e], p[e]);
  }
  __syncthreads();
  if (tid < NE) { atomicAdd(&cnt[tid], bc[tid]); atomicAdd(&psum[tid], bp[tid]); }
}

// ---------------- K2: offsets + aux loss + pad sentinels (256-aligned) ----------------
__global__ void k_offsets(const int* __restrict__ cnt, const float* __restrict__ psum,
                          int* __restrict__ offp, int* __restrict__ pair_tok,
                          float* __restrict__ pair_w, float* __restrict__ loss_out) {
  __shared__ int soff[NE + 1], scnt[NE];
  if (threadIdx.x == 0) {
    int o = 0;
    for (int e = 0; e < NE; ++e) {
      soff[e] = o; scnt[e] = cnt[e];
      o += (scnt[e] + 255) & ~255;
    }
    soff[NE] = o;
    for (int e = 0; e <= NE; ++e) offp[e] = soff[e];
    float loss = 0.f;
    for (int e = 0; e < NE; ++e) loss += psum[e] * (float)scnt[e];
    loss *= (float)NE * 0.01f / ((float)T_TOK * (float)T_TOK);
    *loss_out = loss;
  }
  __syncthreads();
  for (int e = 0; e < NE; ++e) {
    const int base = soff[e] + scnt[e];
    const int n = soff[e + 1] - base;
    for (int j = threadIdx.x; j < n; j += blockDim.x) {
      pair_tok[base + j] = -1;
      pair_w[base + j] = 0.f;
    }
  }
}

// ---------------- K3: compaction (+ inverse map) ----------------
__global__ void k_scatter(const int* __restrict__ tok_e, const float* __restrict__ tok_w,
                          const int* __restrict__ offp, int* __restrict__ cursor,
                          int* __restrict__ pair_tok, float* __restrict__ pair_w,
                          int* __restrict__ inv_p) {
  const int t = blockIdx.x * 256 + threadIdx.x;
#pragma unroll
  for (int k = 0; k < 2; ++k) {
    const int e = tok_e[2 * t + k];
    const int pos = atomicAdd(&cursor[e], 1);
    const int idx = offp[e] + pos;
    pair_tok[idx] = t;
    pair_w[idx] = tok_w[2 * t + k];
    inv_p[2 * t + k] = idx;
  }
}

// ---------------- K4: stage1 — phase-scheduled 256x128 dual-B GEMM + SwiGLU ----------------
// Same verified schedule as previous round; ONLY the LDS swizzle changed:
//   slot = quad ^ ((row>>1)&3)  [was row&3 — that gave 4-way bank conflicts
//   in 64B rows: even colms hit only 2 of 4 slots]. With (row>>1)&3, a 16-lane
//   read group spreads 2 lanes/bank (free per m136). Staging source k-chunk
//   pre-swizzle updated consistently: ks = (l&3) ^ ((l>>3)&3)  [row = w*16 + (l>>2),
//   so (row>>1)&3 == (l>>3)&3].
// LDS ushort map: A [buf][kkh][256][32] @0; Bg [buf][kkh][128][32] @32768; Bu @49152.
#define A_RG(b,h)  ((b) * 16384 + (h) * 8192)
#define BG_RG(b,h) (32768 + (b) * 8192 + (h) * 4096)
#define BU_RG(b,h) (49152 + (b) * 8192 + (h) * 4096)
#define STG_A(b,h,t)  do { gl16(srcA0 + (t) * 64 + (h) * 32, &smem[A_RG(b,h) + wub]); \
                           gl16(srcA1 + (t) * 64 + (h) * 32, &smem[A_RG(b,h) + 4096 + wub]); } while (0)
#define STG_BG(b,h,t) gl16(srcBg + (t) * 64 + (h) * 32, &smem[BG_RG(b,h) + wub])
#define STG_BU(b,h,t) gl16(srcBu + (t) * 64 + (h) * 32, &smem[BU_RG(b,h) + wub])

#define S1_RD_AF(b,k) { _Pragma("unroll") for (int mf_ = 0; mf_ < 4; ++mf_) \
                          af[mf_] = *(const bf16x8*)&smem[A_RG(b,k) + afoff[mf_]]; }
#define S1_RD_BG(b,k) { _Pragma("unroll") for (int nf_ = 0; nf_ < 4; ++nf_) \
                          bg[nf_] = *(const bf16x8*)&smem[BG_RG(b,k) + bnoff[nf_]]; }
#define S1_RD_BU(b,k) { _Pragma("unroll") for (int nf_ = 0; nf_ < 4; ++nf_) \
                          bu[nf_] = *(const bf16x8*)&smem[BU_RG(b,k) + bnoff[nf_]]; }
#define S1_MM(ACC, BF) { _Pragma("unroll") for (int mf_ = 0; mf_ < 4; ++mf_) { \
                           _Pragma("unroll") for (int nf_ = 0; nf_ < 4; ++nf_) \
                             ACC[mf_][nf_] = __builtin_amdgcn_mfma_f32_16x16x32_bf16(af[mf_], BF[nf_], ACC[mf_][nf_], 0, 0, 0); } }

#define S1_TILE(B, KT) do { \
    bf16x8 af[4], bg[4], bu[4]; \
    /* P1: gate kk0 */ \
    S1_RD_AF(B, 0); S1_RD_BG(B, 0); \
    if ((KT) + 1 < 16) STG_BU((B) ^ 1, 1, (KT) + 1); \
    BARRIER; LGKM0; PRIO1; S1_MM(accg, bg); PRIO0; BARRIER; \
    /* P2: up kk0 (af reused) */ \
    S1_RD_BU(B, 0); \
    if ((KT) + 2 < 16) { STG_A(B, 0, (KT) + 2); STG_BG(B, 0, (KT) + 2); } \
    BARRIER; LGKM0; PRIO1; S1_MM(accu, bu); PRIO0; BARRIER; \
    /* P3: gate kk1 */ \
    S1_RD_AF(B, 1); S1_RD_BG(B, 1); \
    if ((KT) + 2 < 16) STG_BU(B, 0, (KT) + 2); \
    BARRIER; LGKM0; PRIO1; S1_MM(accg, bg); PRIO0; BARRIER; \
    /* P4: up kk1 */ \
    S1_RD_BU(B, 1); \
    if ((KT) + 2 < 16) { STG_A(B, 1, (KT) + 2); STG_BG(B, 1, (KT) + 2); } \
    BARRIER; LGKM0; PRIO1; S1_MM(accu, bu); PRIO0; \
    if ((KT) + 2 < 16) { VMCNT(7); } else { VMCNT(0); } \
    BARRIER; \
  } while (0)

__launch_bounds__(512, 2)
__global__ void k_stage1(const unsigned short* __restrict__ xb,
                         const unsigned short* __restrict__ Wgt,
                         const unsigned short* __restrict__ Wut,
                         const int* __restrict__ offp,
                         const int* __restrict__ pair_tok,
                         unsigned short* __restrict__ act) {
  __shared__ __align__(16) unsigned short smem[65536];   // 128 KiB
  __shared__ int toks[256];

  // bijective XCD swizzle over 1584 = 22 x 72 blocks (1584 % 8 == 0)
  int wg = blockIdx.x;
  wg = (wg & 7) * (1584 / 8) + (wg >> 3);
  const int ytile = wg / 22, xtile = wg - ytile * 22;
  const int row0 = ytile * 256;
  if (row0 >= offp[8]) return;
  int e = 0;
  while (offp[e + 1] <= row0) ++e;
  const int i0 = xtile * 128;

  const int tid = threadIdx.x;
  if (tid < 256) {
    const int tk = pair_tok[row0 + tid];
    toks[tid] = tk < 0 ? 0 : tk;
  }
  __syncthreads();

  const int l = tid & 63, w = tid >> 6;
  const int colm = l & 15, quad = l >> 4;
  const int wr = w >> 1, wc = w & 1;

  // staging mapping: wave w covers rows w*16 + l/4; slot l&3; source pre-swizzled
  const int rA0 = w * 16 + (l >> 2);
  const int ks  = (l & 3) ^ ((l >> 3) & 3);     // FIXED: matches (row>>1)&3 read swizzle
  const unsigned short* wgtE = Wgt + (size_t)e * ID * HD;
  const unsigned short* wutE = Wut + (size_t)e * ID * HD;
  const unsigned short* srcA0 = xb + (size_t)toks[rA0] * HD + ks * 8;
  const unsigned short* srcA1 = xb + (size_t)toks[rA0 + 128] * HD + ks * 8;
  const unsigned short* srcBg = wgtE + (size_t)(i0 + rA0) * HD + ks * 8;
  const unsigned short* srcBu = wutE + (size_t)(i0 + rA0) * HD + ks * 8;
  const int wub = w * 512;

  // fragment read offsets: slot = quad ^ ((row>>1)&3); row = base16 + colm
  const int sl = (quad ^ ((colm >> 1) & 3)) * 8;   // FIXED swizzle
  int afoff[4], bnoff[4];
#pragma unroll
  for (int i = 0; i < 4; ++i) {
    afoff[i] = (wr * 64 + i * 16 + colm) * 32 + sl;
    bnoff[i] = (wc * 64 + i * 16 + colm) * 32 + sl;
  }

  const f32x4 zero = {0.f, 0.f, 0.f, 0.f};
  f32x4 accg[4][4], accu[4][4];
#pragma unroll
  for (int a = 0; a < 4; ++a)
#pragma unroll
    for (int b = 0; b < 4; ++b) { accg[a][b] = zero; accu[a][b] = zero; }

  // prologue: tile0 full (8 rounds), tile1 minus Bu-kk1 (7 rounds)
  STG_A(0, 0, 0); STG_BG(0, 0, 0); STG_BU(0, 0, 0);
  STG_A(0, 1, 0); STG_BG(0, 1, 0); STG_BU(0, 1, 0);
  STG_A(1, 0, 1); STG_BG(1, 0, 1); STG_BU(1, 0, 1);
  STG_A(1, 1, 1); STG_BG(1, 1, 1);
  VMCNT(7); BARRIER;

  for (int kt = 0; kt < 16; kt += 2) {
    S1_TILE(0, kt);
    S1_TILE(1, kt + 1);
  }

  // epilogue: SwiGLU, write bf16 activations
#pragma unroll
  for (int mf = 0; mf < 4; ++mf) {
#pragma unroll
    for (int r = 0; r < 4; ++r) {
      const int orow = row0 + wr * 64 + mf * 16 + quad * 4 + r;
      unsigned short* arow = act + (size_t)orow * ID + i0 + wc * 64 + colm;
#pragma unroll
      for (int nf = 0; nf < 4; ++nf) {
        const float g = accg[mf][nf][r];
        const float u = accu[mf][nf][r];
        const float h = (g / (1.f + __expf(-g))) * u;
        arow[nf * 16] = f2bf(h);
      }
    }
  }
}

// ---------------- K5: stage2 — phase-scheduled 256x128 down GEMM ----------------
// Same verified schedule as previous round; swizzle fixed identically to stage1.
// LDS ushort map: A [buf][kkh][256][32] @0; B [buf][kkh][128][32] @32768. 96 KiB.
#define A2_RG(b,h) ((b) * 16384 + (h) * 8192)
#define B2_RG(b,h) (32768 + (b) * 8192 + (h) * 4096)
#define STG2_A(b,h,t) do { gl16(srcA0 + (t) * 64 + (h) * 32, &smem[A2_RG(b,h) + wub]); \
                           gl16(srcA1 + (t) * 64 + (h) * 32, &smem[A2_RG(b,h) + 4096 + wub]); } while (0)
#define STG2_B(b,h,t) gl16(srcB + (t) * 64 + (h) * 32, &smem[B2_RG(b,h) + wub])

#define S2_RD_AF(b,k) { _Pragma("unroll") for (int mf_ = 0; mf_ < 4; ++mf_) \
                          af[mf_] = *(const bf16x8*)&smem[A2_RG(b,k) + afoff[mf_]]; }
#define S2_RD_BF(b,k) { _Pragma("unroll") for (int nf_ = 0; nf_ < 4; ++nf_) \
                          bf_[nf_] = *(const bf16x8*)&smem[B2_RG(b,k) + bnoff[nf_]]; }
#define S2_MM { _Pragma("unroll") for (int mf_ = 0; mf_ < 4; ++mf_) { \
                  _Pragma("unroll") for (int nf_ = 0; nf_ < 4; ++nf_) \
                    acc[mf_][nf_] = __builtin_amdgcn_mfma_f32_16x16x32_bf16(af[mf_], bf_[nf_], acc[mf_][nf_], 0, 0, 0); } }

#define S2_TILE(B, T) do { \
    bf16x8 af[4], bf_[4]; \
    /* P1: kk0 */ \
    S2_RD_AF(B, 0); S2_RD_BF(B, 0); \
    if ((T) + 1 < 44) { STG2_A((B) ^ 1, 1, (T) + 1); STG2_B((B) ^ 1, 1, (T) + 1); } \
    BARRIER; LGKM0; PRIO1; S2_MM; PRIO0; \
    if ((T) + 1 < 44) { VMCNT(6); } else { VMCNT(0); } \
    BARRIER; \
    /* P2: kk1 */ \
    S2_RD_AF(B, 1); S2_RD_BF(B, 1); \
    if ((T) + 2 < 44) { STG2_A(B, 0, (T) + 2); STG2_B(B, 0, (T) + 2); } \
    BARRIER; LGKM0; PRIO1; S2_MM; PRIO0; \
    if ((T) + 2 < 44) { VMCNT(6); } else if ((T) + 1 < 44) { VMCNT(3); } else { VMCNT(0); } \
    BARRIER; \
  } while (0)

template <bool USE_CONTRIB>
__launch_bounds__(512, 2)
__global__ void k_stage2_t(const unsigned short* __restrict__ act,
                           const unsigned short* __restrict__ Wdt,
                           const int* __restrict__ offp,
                           const int* __restrict__ pair_tok,
                           const float* __restrict__ pair_w,
                           float* __restrict__ contrib,   // USE_CONTRIB: [RCAP][HD]
                           float* __restrict__ out) {     // !USE_CONTRIB: atomic path
  __shared__ __align__(16) unsigned short smem[49152];    // 96 KiB
  __shared__ int toks[256];
  __shared__ float wts[256];

  // bijective XCD swizzle over 576 = 8 x 72 blocks
  int wg = blockIdx.x;
  wg = (wg & 7) * (576 / 8) + (wg >> 3);
  const int ytile = wg >> 3, xtile = wg & 7;
  const int row0 = ytile * 256;
  if (row0 >= offp[8]) return;
  int e = 0;
  while (offp[e + 1] <= row0) ++e;
  const int h0 = xtile * 128;
  const int tid = threadIdx.x;
  if (!USE_CONTRIB && tid < 256) {
    toks[tid] = pair_tok[row0 + tid];
    wts[tid] = pair_w[row0 + tid];
  }

  const int l = tid & 63, w = tid >> 6;
  const int colm = l & 15, quad = l >> 4;
  const int wr = w >> 1, wc = w & 1;
  const int rA0 = w * 16 + (l >> 2);
  const int ks = (l & 3) ^ ((l >> 3) & 3);      // FIXED: matches (row>>1)&3 read swizzle
  const unsigned short* wdE = Wdt + (size_t)e * HD * ID;
  const unsigned short* srcA0 = act + (size_t)(row0 + rA0) * ID + ks * 8;
  const unsigned short* srcA1 = act + (size_t)(row0 + rA0 + 128) * ID + ks * 8;
  const unsigned short* srcB  = wdE + (size_t)(h0 + rA0) * ID + ks * 8;
  const int wub = w * 512;
  const int sl = (quad ^ ((colm >> 1) & 3)) * 8;   // FIXED swizzle
  int afoff[4], bnoff[4];
#pragma unroll
  for (int i = 0; i < 4; ++i) {
    afoff[i] = (wr * 64 + i * 16 + colm) * 32 + sl;
    bnoff[i] = (wc * 64 + i * 16 + colm) * 32 + sl;
  }

  const f32x4 zero = {0.f, 0.f, 0.f, 0.f};
  f32x4 acc[4][4];
#pragma unroll
  for (int a = 0; a < 4; ++a)
#pragma unroll
    for (int b = 0; b < 4; ++b) acc[a][b] = zero;

  // prologue: tile0 full (6 rounds), tile1 kk0 (3 rounds); kk1 of tile1 staged at T0-P1
  STG2_A(0, 0, 0); STG2_B(0, 0, 0);
  STG2_A(0, 1, 0); STG2_B(0, 1, 0);
  STG2_A(1, 0, 1); STG2_B(1, 0, 1);
  VMCNT(3); BARRIER;

  for (int T = 0; T < 44; T += 2) {
    S2_TILE(0, T);
    S2_TILE(1, T + 1);
  }

#pragma unroll
  for (int mf = 0; mf < 4; ++mf) {
#pragma unroll
    for (int r = 0; r < 4; ++r) {
      const int lrow = wr * 64 + mf * 16 + quad * 4 + r;
      if (USE_CONTRIB) {
        float* crow = contrib + (size_t)(row0 + lrow) * HD + h0 + wc * 64 + colm;
#pragma unroll
        for (int nf = 0; nf < 4; ++nf)
          crow[nf * 16] = acc[mf][nf][r];
      } else {
        const int t = toks[lrow];
        if (t < 0) continue;
        const float wt = wts[lrow];
        float* orow = out + (size_t)t * HD + h0 + wc * 64 + colm;
#pragma unroll
        for (int nf = 0; nf < 4; ++nf)
          atomicAdd(&orow[nf * 16], wt * acc[mf][nf][r]);
      }
    }
  }
}

// ---------------- K6: combine (contrib path) ----------------
__global__ void k_combine(const float* __restrict__ contrib, const int* __restrict__ inv_p,
                          const float* __restrict__ tok_w, float* __restrict__ out) {
  const int t = blockIdx.x;
  const int h4 = threadIdx.x;
  const int p0 = inv_p[2 * t], p1 = inv_p[2 * t + 1];
  const float w0 = tok_w[2 * t], w1 = tok_w[2 * t + 1];
  const float4 a = ((const float4*)(contrib + (size_t)p0 * HD))[h4];
  const float4 b = ((const float4*)(contrib + (size_t)p1 * HD))[h4];
  float4 o;
  o.x = w0 * a.x + w1 * b.x;
  o.y = w0 * a.y + w1 * b.y;
  o.z = w0 * a.z + w1 * b.z;
  o.w = w0 * a.w + w1 * b.w;
  ((float4*)(out + (size_t)t * HD))[h4] = o;
}

extern "C" void kernel_launch(void* const* d_in, const int* in_sizes, int n_in,
                              void* d_out, int out_size, void* d_ws, size_t ws_size,
                              hipStream_t stream) {
  const float* x  = (const float*)d_in[0];
  const float* Wr = (const float*)d_in[1];
  const float* Wg = (const float*)d_in[2];
  const float* Wu = (const float*)d_in[3];
  const float* Wd = (const float*)d_in[4];
  float* out = (float*)d_out;

  char* ws = (char*)d_ws;
  const size_t off_xb  = 256;
  const size_t sz_xb   = (size_t)T_TOK * HD * 2;
  const size_t sz_w    = (size_t)NE * HD * ID * 2;
  const size_t off_wgt = off_xb + sz_xb;
  const size_t off_wut = off_wgt + sz_w;
  const size_t off_wdt = off_wut + sz_w;
  const size_t off_act = off_wdt + sz_w;
  const size_t sz_act  = (size_t)RCAP * ID * 2;
  const size_t off_ptk = off_act + sz_act;
  const size_t off_pw  = off_ptk + (size_t)RCAP * 4;
  const size_t off_te  = off_pw + (size_t)RCAP * 4;
  const size_t off_tw  = off_te + (size_t)T_TOK * 2 * 4;
  const size_t off_ip  = off_tw + (size_t)T_TOK * 2 * 4;
  const size_t off_ctb = off_ip + (size_t)T_TOK * 2 * 4;
  const size_t need_base = off_ctb;
  const size_t need_full = off_ctb + (size_t)RCAP * HD * 4;
  if (ws_size < need_base) return;
  const bool use_contrib = (ws_size >= need_full);

  int*   cnt    = (int*)(ws + 0);
  float* psum   = (float*)(ws + 32);
  int*   cursor = (int*)(ws + 64);
  int*   offp   = (int*)(ws + 96);
  unsigned short* xb  = (unsigned short*)(ws + off_xb);
  unsigned short* Wgt = (unsigned short*)(ws + off_wgt);
  unsigned short* Wut = (unsigned short*)(ws + off_wut);
  unsigned short* Wdt = (unsigned short*)(ws + off_wdt);
  unsigned short* act = (unsigned short*)(ws + off_act);
  int*   pair_tok = (int*)(ws + off_ptk);
  float* pair_w   = (float*)(ws + off_pw);
  int*   tok_e    = (int*)(ws + off_te);
  float* tok_w    = (float*)(ws + off_tw);
  int*   inv_p    = (int*)(ws + off_ip);
  float* contrib  = (float*)(ws + off_ctb);

  hipMemsetAsync(ws, 0, 256, stream);
  if (!use_contrib)
    hipMemsetAsync(out, 0, (size_t)T_TOK * HD * sizeof(float), stream);

  k_cvt_x<<<(T_TOK * HD / 4) / 256, 256, 0, stream>>>(x, xb);
  k_transpose<<<dim3(704, 24), 256, 0, stream>>>(Wg, Wu, Wd, Wgt, Wut, Wdt);
  k_router<<<T_TOK / 4, 256, 0, stream>>>(x, Wr, cnt, psum, tok_e, tok_w);
  k_offsets<<<1, 256, 0, stream>>>(cnt, psum, offp, pair_tok, pair_w, out + (size_t)T_TOK * HD);
  k_scatter<<<T_TOK / 256, 256, 0, stream>>>(tok_e, tok_w, offp, cursor, pair_tok, pair_w, inv_p);
  k_stage1<<<(ID / 128) * (RCAP / 256), 512, 0, stream>>>(xb, Wgt, Wut, offp, pair_tok, act);
  if (use_contrib) {
    k_stage2_t<true><<<(HD / 128) * (RCAP / 256), 512, 0, stream>>>(act, Wdt, offp, pair_tok, pair_w, contrib, out);
    k_combine<<<T_TOK, 256, 0, stream>>>(contrib, inv_p, tok_w, out);
  } else {
    k_stage2_t<false><<<(HD / 128) * (RCAP / 256), 512, 0, stream>>>(act, Wdt, offp, pair_tok, pair_w, contrib, out);
  }
}

// Round 3
// 820.336 us; speedup vs baseline: 1.3406x; 1.3101x over previous
//
#include <hip/hip_runtime.h>
#include <stdint.h>

#define T_TOK 8192
#define HD    1024
#define ID    2816
#define NE    8
#define RCAP  17408   // 16384 pairs + up to 8*128 padding

typedef __bf16 bf16x8 __attribute__((ext_vector_type(8)));
typedef float  f32x4  __attribute__((ext_vector_type(4)));

__device__ __forceinline__ unsigned short f2bf(float f) {
  union { float f; unsigned u; } v; v.f = f;
  unsigned r = v.u + 0x7FFFu + ((v.u >> 16) & 1u);  // round-to-nearest-even
  return (unsigned short)(r >> 16);
}

__device__ __forceinline__ void gl16(const void* g, void* l) {
  __builtin_amdgcn_global_load_lds((__attribute__((address_space(1))) void*)g,
                                   (__attribute__((address_space(3))) void*)l,
                                   16, 0, 0);
}

// ---------------- K0b: transpose + convert weights ----------------
// 4x4 register-block transpose, XOR slot swizzle in LDS (b64 ops, <=4-way)
__global__ void k_transpose(const float* __restrict__ Wg, const float* __restrict__ Wu,
                            const float* __restrict__ Wd,
                            unsigned short* __restrict__ Wgt, unsigned short* __restrict__ Wut,
                            unsigned short* __restrict__ Wdt) {
  const int m = blockIdx.y;
  const float* src; unsigned short* dst; int R, C;
  if (m < 8)       { src = Wg + (size_t)m * HD * ID;        dst = Wgt + (size_t)m * HD * ID;        R = HD; C = ID; }
  else if (m < 16) { src = Wu + (size_t)(m - 8) * HD * ID;  dst = Wut + (size_t)(m - 8) * HD * ID;  R = HD; C = ID; }
  else             { src = Wd + (size_t)(m - 16) * HD * ID; dst = Wdt + (size_t)(m - 16) * HD * ID; R = ID; C = HD; }
  const int tc = C / 64;
  const int tr = blockIdx.x / tc, tcc = blockIdx.x % tc;
  const int r0 = tr * 64, c0 = tcc * 64;
  __shared__ __align__(16) unsigned short tl[64 * 64];  // [dst_row][slot^swz]
  const int t = threadIdx.x;
  const int rb = t >> 4;       // source row block 0..15
  const int c4 = t & 15;       // source col block 0..15
  const float* sp = src + (size_t)(r0 + rb * 4) * C + c0 + c4 * 4;
  float4 v[4];
#pragma unroll
  for (int i = 0; i < 4; ++i) v[i] = *(const float4*)(sp + (size_t)i * C);
  const float* vf = (const float*)v;
#pragma unroll
  for (int q = 0; q < 4; ++q) {
    const int c = c4 * 4 + q;                 // dst row
    ushort4 o;
    o.x = f2bf(vf[0 * 4 + q]); o.y = f2bf(vf[1 * 4 + q]);
    o.z = f2bf(vf[2 * 4 + q]); o.w = f2bf(vf[3 * 4 + q]);
    *(ushort4*)&tl[c * 64 + ((rb ^ (c & 15)) * 4)] = o;   // dst cols rb*4..rb*4+3
  }
  __syncthreads();
  const int orow = t >> 2, seg = t & 3;
  __align__(16) unsigned short tmp[16];
#pragma unroll
  for (int mI = 0; mI < 4; ++mI) {
    const int s = seg * 4 + mI;
    *(ushort4*)&tmp[mI * 4] = *(const ushort4*)&tl[orow * 64 + ((s ^ (orow & 15)) * 4)];
  }
  unsigned short* dp = dst + (size_t)(c0 + orow) * R + r0 + seg * 16;
  ((uint4*)dp)[0] = ((const uint4*)tmp)[0];
  ((uint4*)dp)[1] = ((const uint4*)tmp)[1];
}

// ---------------- K1: router (1 token per wave) + fused x->bf16 ----------------
__global__ void k_router(const float* __restrict__ x, const float* __restrict__ Wr,
                         int* __restrict__ cnt, float* __restrict__ psum,
                         int* __restrict__ tok_e, float* __restrict__ tok_w,
                         unsigned short* __restrict__ xb) {
  __shared__ float bp[NE];
  __shared__ int bc[NE];
  const int tid = threadIdx.x;
  if (tid < NE) { bp[tid] = 0.f; bc[tid] = 0; }
  __syncthreads();
  const int lane = tid & 63, w = tid >> 6;
  const int t = blockIdx.x * 4 + w;
  float acc[NE] = {0.f, 0.f, 0.f, 0.f, 0.f, 0.f, 0.f, 0.f};
  for (int h = lane; h < HD; h += 64) {
    const float xv = x[(size_t)t * HD + h];
    xb[(size_t)t * HD + h] = f2bf(xv);       // fused conversion (coalesced 128B/wave)
    const float4 w0 = *(const float4*)(Wr + h * 8);
    const float4 w1 = *(const float4*)(Wr + h * 8 + 4);
    acc[0] += xv * w0.x; acc[1] += xv * w0.y; acc[2] += xv * w0.z; acc[3] += xv * w0.w;
    acc[4] += xv * w1.x; acc[5] += xv * w1.y; acc[6] += xv * w1.z; acc[7] += xv * w1.w;
  }
#pragma unroll
  for (int e = 0; e < NE; ++e)
    for (int off = 32; off > 0; off >>= 1)
      acc[e] += __shfl_xor(acc[e], off, 64);
  if (lane == 0) {
    float mx = acc[0];
    for (int e = 1; e < NE; ++e) mx = fmaxf(mx, acc[e]);
    float p[NE], s = 0.f;
    for (int e = 0; e < NE; ++e) { p[e] = __expf(acc[e] - mx); s += p[e]; }
    const float inv = 1.f / s;
    for (int e = 0; e < NE; ++e) p[e] *= inv;
    int e0 = 0;
    for (int e = 1; e < NE; ++e) if (p[e] > p[e0]) e0 = e;
    int e1 = (e0 == 0) ? 1 : 0;
    for (int e = 0; e < NE; ++e) if (e != e0 && p[e] > p[e1]) e1 = e;
    const float v0 = p[e0], v1 = p[e1];
    const float invs = 1.f / (v0 + v1 + 1e-9f);
    tok_e[2 * t] = e0;          tok_e[2 * t + 1] = e1;
    tok_w[2 * t] = v0 * invs;   tok_w[2 * t + 1] = v1 * invs;
    atomicAdd(&bc[e0], 1); atomicAdd(&bc[e1], 1);
    for (int e = 0; e < NE; ++e) atomicAdd(&bp[e], p[e]);
  }
  __syncthreads();
  if (tid < NE) { atomicAdd(&cnt[tid], bc[tid]); atomicAdd(&psum[tid], bp[tid]); }
}

// ---------------- K2: offsets + aux loss + pad sentinels ----------------
__global__ void k_offsets(const int* __restrict__ cnt, const float* __restrict__ psum,
                          int* __restrict__ offp, int* __restrict__ pair_tok,
                          float* __restrict__ pair_w, float* __restrict__ loss_out) {
  __shared__ int soff[NE + 1], scnt[NE];
  if (threadIdx.x == 0) {
    int o = 0;
    for (int e = 0; e < NE; ++e) {
      soff[e] = o; scnt[e] = cnt[e];
      o += (scnt[e] + 127) & ~127;
    }
    soff[NE] = o;
    for (int e = 0; e <= NE; ++e) offp[e] = soff[e];
    float loss = 0.f;
    for (int e = 0; e < NE; ++e) loss += psum[e] * (float)scnt[e];
    loss *= (float)NE * 0.01f / ((float)T_TOK * (float)T_TOK);
    *loss_out = loss;
  }
  __syncthreads();
  for (int e = 0; e < NE; ++e) {
    const int base = soff[e] + scnt[e];
    const int n = soff[e + 1] - base;
    for (int j = threadIdx.x; j < n; j += blockDim.x) {
      pair_tok[base + j] = -1;
      pair_w[base + j] = 0.f;
    }
  }
}

// ---------------- K3: compaction (+ inverse map) ----------------
__global__ void k_scatter(const int* __restrict__ tok_e, const float* __restrict__ tok_w,
                          const int* __restrict__ offp, int* __restrict__ cursor,
                          int* __restrict__ pair_tok, float* __restrict__ pair_w,
                          int* __restrict__ inv_p) {
  const int t = blockIdx.x * 256 + threadIdx.x;
#pragma unroll
  for (int k = 0; k < 2; ++k) {
    const int e = tok_e[2 * t + k];
    const int pos = atomicAdd(&cursor[e], 1);
    const int idx = offp[e] + pos;
    pair_tok[idx] = t;
    pair_w[idx] = tok_w[2 * t + k];
    inv_p[2 * t + k] = idx;
  }
}

// ---------------- K4: stage1 fused gate+up GEMM + SwiGLU ----------------
__launch_bounds__(256, 2)
__global__ void k_stage1(const unsigned short* __restrict__ xb,
                         const unsigned short* __restrict__ Wgt,
                         const unsigned short* __restrict__ Wut,
                         const int* __restrict__ offp,
                         const int* __restrict__ pair_tok,
                         unsigned short* __restrict__ act) {
  __shared__ __align__(16) unsigned short lA[8192];
  __shared__ __align__(16) unsigned short lBg[8192];
  __shared__ __align__(16) unsigned short lBu[8192];
  __shared__ int toks[128];

  const int row0 = blockIdx.y * 128;
  if (row0 >= offp[8]) return;
  int e = 0;
  while (offp[e + 1] <= row0) ++e;
  const int i0 = blockIdx.x * 128;
  const int tid = threadIdx.x;
  if (tid < 128) {
    const int tk = pair_tok[row0 + tid];
    toks[tid] = tk < 0 ? 0 : tk;
  }
  __syncthreads();

  const int lane = tid & 63, w = tid >> 6;
  const unsigned short* gA[4];
  const unsigned short* gBg[4];
  const unsigned short* gBu[4];
  unsigned ldso[4];
  const unsigned short* wgtE = Wgt + (size_t)e * ID * HD;
  const unsigned short* wutE = Wut + (size_t)e * ID * HD;
#pragma unroll
  for (int j = 0; j < 4; ++j) {
    const int row = (w * 4 + j) * 8 + (lane >> 3);
    const int kb = (lane & 7) ^ (row & 7);
    gA[j]  = xb + (size_t)toks[row] * HD + kb * 8;
    gBg[j] = wgtE + (size_t)(i0 + row) * HD + kb * 8;
    gBu[j] = wutE + (size_t)(i0 + row) * HD + kb * 8;
    ldso[j] = (unsigned)(w * 4 + j) * 512u;
  }

  const f32x4 zero = {0.f, 0.f, 0.f, 0.f};
  f32x4 accg[4][4], accu[4][4];
#pragma unroll
  for (int a = 0; a < 4; ++a)
#pragma unroll
    for (int b = 0; b < 4; ++b) { accg[a][b] = zero; accu[a][b] = zero; }

  const int wm = (w & 1) * 64, wn = (w >> 1) * 64;
  const int colm = lane & 15, quad = lane >> 4;

  for (int kt = 0; kt < HD / 64; ++kt) {
    __syncthreads();
    const int ko = kt * 64;
#pragma unroll
    for (int j = 0; j < 4; ++j) {
      gl16(gA[j] + ko,  &lA[ldso[j]]);
      gl16(gBg[j] + ko, &lBg[ldso[j]]);
      gl16(gBu[j] + ko, &lBu[ldso[j]]);
    }
    __syncthreads();
#pragma unroll
    for (int kk = 0; kk < 2; ++kk) {
      const int kbl = kk * 4 + quad;
      bf16x8 af[4], bg[4], bu[4];
#pragma unroll
      for (int mf = 0; mf < 4; ++mf) {
        const int r = wm + mf * 16 + colm;
        af[mf] = *(const bf16x8*)&lA[r * 64 + ((kbl ^ (r & 7)) * 8)];
      }
#pragma unroll
      for (int nf = 0; nf < 4; ++nf) {
        const int r = wn + nf * 16 + colm;
        const int o = r * 64 + ((kbl ^ (r & 7)) * 8);
        bg[nf] = *(const bf16x8*)&lBg[o];
        bu[nf] = *(const bf16x8*)&lBu[o];
      }
#pragma unroll
      for (int mf = 0; mf < 4; ++mf)
#pragma unroll
        for (int nf = 0; nf < 4; ++nf) {
          accg[mf][nf] = __builtin_amdgcn_mfma_f32_16x16x32_bf16(af[mf], bg[nf], accg[mf][nf], 0, 0, 0);
          accu[mf][nf] = __builtin_amdgcn_mfma_f32_16x16x32_bf16(af[mf], bu[nf], accu[mf][nf], 0, 0, 0);
        }
    }
  }

#pragma unroll
  for (int mf = 0; mf < 4; ++mf) {
#pragma unroll
    for (int r = 0; r < 4; ++r) {
      const int orow = row0 + wm + mf * 16 + quad * 4 + r;
      unsigned short* arow = act + (size_t)orow * ID + i0 + wn + colm;
#pragma unroll
      for (int nf = 0; nf < 4; ++nf) {
        const float g = accg[mf][nf][r];
        const float u = accu[mf][nf][r];
        const float h = (g / (1.f + __expf(-g))) * u;
        arow[nf * 16] = f2bf(h);
      }
    }
  }
}

// ---------------- K5 core: stage2 down GEMM ----------------
template <bool USE_CONTRIB>
__launch_bounds__(256, 2)
__global__ void k_stage2_t(const unsigned short* __restrict__ act,
                           const unsigned short* __restrict__ Wdt,
                           const int* __restrict__ offp,
                           const int* __restrict__ pair_tok,
                           const float* __restrict__ pair_w,
                           float* __restrict__ contrib,   // USE_CONTRIB: [RCAP][HD]
                           float* __restrict__ out) {     // !USE_CONTRIB: atomic path
  __shared__ __align__(16) unsigned short lA[8192];
  __shared__ __align__(16) unsigned short lB[8192];
  __shared__ int toks[128];
  __shared__ float wts[128];

  const int row0 = blockIdx.y * 128;
  if (row0 >= offp[8]) return;
  int e = 0;
  while (offp[e + 1] <= row0) ++e;
  const int h0 = blockIdx.x * 128;
  const int tid = threadIdx.x;
  if (!USE_CONTRIB && tid < 128) {
    toks[tid] = pair_tok[row0 + tid];
    wts[tid] = pair_w[row0 + tid];
  }
  const int lane = tid & 63, w = tid >> 6;
  const unsigned short* gA[4];
  const unsigned short* gB[4];
  unsigned ldso[4];
  const unsigned short* wdE = Wdt + (size_t)e * HD * ID;
#pragma unroll
  for (int j = 0; j < 4; ++j) {
    const int row = (w * 4 + j) * 8 + (lane >> 3);
    const int kb = (lane & 7) ^ (row & 7);
    gA[j] = act + (size_t)(row0 + row) * ID + kb * 8;
    gB[j] = wdE + (size_t)(h0 + row) * ID + kb * 8;
    ldso[j] = (unsigned)(w * 4 + j) * 512u;
  }

  const f32x4 zero = {0.f, 0.f, 0.f, 0.f};
  f32x4 acc[4][4];
#pragma unroll
  for (int a = 0; a < 4; ++a)
#pragma unroll
    for (int b = 0; b < 4; ++b) acc[a][b] = zero;

  const int wm = (w & 1) * 64, wn = (w >> 1) * 64;
  const int colm = lane & 15, quad = lane >> 4;

  for (int kt = 0; kt < ID / 64; ++kt) {
    __syncthreads();
    const int ko = kt * 64;
#pragma unroll
    for (int j = 0; j < 4; ++j) {
      gl16(gA[j] + ko, &lA[ldso[j]]);
      gl16(gB[j] + ko, &lB[ldso[j]]);
    }
    __syncthreads();
#pragma unroll
    for (int kk = 0; kk < 2; ++kk) {
      const int kbl = kk * 4 + quad;
      bf16x8 af[4], bf_[4];
#pragma unroll
      for (int mf = 0; mf < 4; ++mf) {
        const int r = wm + mf * 16 + colm;
        af[mf] = *(const bf16x8*)&lA[r * 64 + ((kbl ^ (r & 7)) * 8)];
      }
#pragma unroll
      for (int nf = 0; nf < 4; ++nf) {
        const int r = wn + nf * 16 + colm;
        bf_[nf] = *(const bf16x8*)&lB[r * 64 + ((kbl ^ (r & 7)) * 8)];
      }
#pragma unroll
      for (int mf = 0; mf < 4; ++mf)
#pragma unroll
        for (int nf = 0; nf < 4; ++nf)
          acc[mf][nf] = __builtin_amdgcn_mfma_f32_16x16x32_bf16(af[mf], bf_[nf], acc[mf][nf], 0, 0, 0);
    }
  }

#pragma unroll
  for (int mf = 0; mf < 4; ++mf) {
#pragma unroll
    for (int r = 0; r < 4; ++r) {
      const int lrow = wm + mf * 16 + quad * 4 + r;
      if (USE_CONTRIB) {
        float* crow = contrib + (size_t)(row0 + lrow) * HD + h0 + wn + colm;
#pragma unroll
        for (int nf = 0; nf < 4; ++nf)
          crow[nf * 16] = acc[mf][nf][r];
      } else {
        const int t = toks[lrow];
        if (t < 0) continue;
        const float wt = wts[lrow];
        float* orow = out + (size_t)t * HD + h0 + wn + colm;
#pragma unroll
        for (int nf = 0; nf < 4; ++nf)
          atomicAdd(&orow[nf * 16], wt * acc[mf][nf][r]);
      }
    }
  }
}

// ---------------- K6: combine (contrib path) ----------------
__global__ void k_combine(const float* __restrict__ contrib, const int* __restrict__ inv_p,
                          const float* __restrict__ tok_w, float* __restrict__ out) {
  const int t = blockIdx.x;
  const int h4 = threadIdx.x;
  const int p0 = inv_p[2 * t], p1 = inv_p[2 * t + 1];
  const float w0 = tok_w[2 * t], w1 = tok_w[2 * t + 1];
  const float4 a = ((const float4*)(contrib + (size_t)p0 * HD))[h4];
  const float4 b = ((const float4*)(contrib + (size_t)p1 * HD))[h4];
  float4 o;
  o.x = w0 * a.x + w1 * b.x;
  o.y = w0 * a.y + w1 * b.y;
  o.z = w0 * a.z + w1 * b.z;
  o.w = w0 * a.w + w1 * b.w;
  ((float4*)(out + (size_t)t * HD))[h4] = o;
}

extern "C" void kernel_launch(void* const* d_in, const int* in_sizes, int n_in,
                              void* d_out, int out_size, void* d_ws, size_t ws_size,
                              hipStream_t stream) {
  const float* x  = (const float*)d_in[0];
  const float* Wr = (const float*)d_in[1];
  const float* Wg = (const float*)d_in[2];
  const float* Wu = (const float*)d_in[3];
  const float* Wd = (const float*)d_in[4];
  float* out = (float*)d_out;

  char* ws = (char*)d_ws;
  const size_t off_xb  = 256;
  const size_t sz_xb   = (size_t)T_TOK * HD * 2;
  const size_t sz_w    = (size_t)NE * HD * ID * 2;
  const size_t off_wgt = off_xb + sz_xb;
  const size_t off_wut = off_wgt + sz_w;
  const size_t off_wdt = off_wut + sz_w;
  const size_t off_act = off_wdt + sz_w;
  const size_t sz_act  = (size_t)RCAP * ID * 2;
  const size_t off_ptk = off_act + sz_act;
  const size_t off_pw  = off_ptk + (size_t)RCAP * 4;
  const size_t off_te  = off_pw + (size_t)RCAP * 4;
  const size_t off_tw  = off_te + (size_t)T_TOK * 2 * 4;
  const size_t off_ip  = off_tw + (size_t)T_TOK * 2 * 4;
  const size_t off_ctb = off_ip + (size_t)T_TOK * 2 * 4;
  const size_t need_base = off_ctb;
  const size_t need_full = off_ctb + (size_t)RCAP * HD * 4;
  if (ws_size < need_base) return;
  const bool use_contrib = (ws_size >= need_full);

  int*   cnt    = (int*)(ws + 0);
  float* psum   = (float*)(ws + 32);
  int*   cursor = (int*)(ws + 64);
  int*   offp   = (int*)(ws + 96);
  unsigned short* xb  = (unsigned short*)(ws + off_xb);
  unsigned short* Wgt = (unsigned short*)(ws + off_wgt);
  unsigned short* Wut = (unsigned short*)(ws + off_wut);
  unsigned short* Wdt = (unsigned short*)(ws + off_wdt);
  unsigned short* act = (unsigned short*)(ws + off_act);
  int*   pair_tok = (int*)(ws + off_ptk);
  float* pair_w   = (float*)(ws + off_pw);
  int*   tok_e    = (int*)(ws + off_te);
  float* tok_w    = (float*)(ws + off_tw);
  int*   inv_p    = (int*)(ws + off_ip);
  float* contrib  = (float*)(ws + off_ctb);

  hipMemsetAsync(ws, 0, 256, stream);
  if (!use_contrib)
    hipMemsetAsync(out, 0, (size_t)T_TOK * HD * sizeof(float), stream);

  k_transpose<<<dim3(704, 24), 256, 0, stream>>>(Wg, Wu, Wd, Wgt, Wut, Wdt);
  k_router<<<T_TOK / 4, 256, 0, stream>>>(x, Wr, cnt, psum, tok_e, tok_w, xb);
  k_offsets<<<1, 256, 0, stream>>>(cnt, psum, offp, pair_tok, pair_w, out + (size_t)T_TOK * HD);
  k_scatter<<<T_TOK / 256, 256, 0, stream>>>(tok_e, tok_w, offp, cursor, pair_tok, pair_w, inv_p);
  k_stage1<<<dim3(ID / 128, RCAP / 128), 256, 0, stream>>>(xb, Wgt, Wut, offp, pair_tok, act);
  if (use_contrib) {
    k_stage2_t<true><<<dim3(HD / 128, RCAP / 128), 256, 0, stream>>>(act, Wdt, offp, pair_tok, pair_w, contrib, out);
    k_combine<<<T_TOK, 256, 0, stream>>>(contrib, inv_p, tok_w, out);
  } else {
    k_stage2_t<false><<<dim3(HD / 128, RCAP / 128), 256, 0, stream>>>(act, Wdt, offp, pair_tok, pair_w, contrib, out);
  }
}